// Round 4
// baseline (88.862 us; speedup 1.0000x reference)
//
#include <hip/hip_runtime.h>
#include <hip/hip_bf16.h>

#define B_ 8
#define C_ 64
#define O_ 64
#define H_ 128
#define W_ 128

typedef __attribute__((ext_vector_type(8))) short bf16x8;
typedef __attribute__((ext_vector_type(4))) float f32x4;

__device__ __forceinline__ unsigned short f2bf(float v) {
    unsigned u = __float_as_uint(v);
    return (unsigned short)((u + 0x7FFFu + ((u >> 16) & 1u)) >> 16);
}

__device__ __forceinline__ int swz(int col) {   // 16B slot selector, 0..112
    return ((col ^ (col >> 3)) & 7) << 4;
}

// ---- weight prep: wfrag flat = (((t*2+ks)*4+fi)*64 + lane)*8 + j ----
// o = fi*16 + (lane&15), c = ks*32 + ((lane>>4)&3)*8 + j  (MFMA B-frag order)
__global__ void prep_weights(const float* __restrict__ weight,
                             unsigned short* __restrict__ wfrag) {
    int idx = blockIdx.x * 256 + threadIdx.x;
    if (idx >= 9 * 4096) return;
    int j  = idx & 7;
    int l  = (idx >> 3) & 63;
    int fi = (idx >> 9) & 3;
    int ks = (idx >> 11) & 1;
    int t  = idx >> 12;
    int o  = fi * 16 + (l & 15);
    int c  = ks * 32 + ((l >> 4) & 3) * 8 + j;
    wfrag[idx] = f2bf(weight[(o * C_ + c) * 9 + t]);
}

// Block: (b, 4-row group, 32-col quarter). 4 waves, wave = output row.
// x LDS: bf16 c-innermost: byte(rc = r*34+col, c) = rc*128 + ((2c) ^ swz(col))
__global__ __launch_bounds__(256, 4)
void depthconv_mfma5(const float* __restrict__ x,
                     const float* __restrict__ depth,
                     const unsigned short* __restrict__ wfrag,
                     const float* __restrict__ bias,
                     float* __restrict__ out) {
    __shared__ __align__(16) unsigned char xs[204 * 128];   // 26112 B
    __shared__ __align__(16) float sim[9][4][32];           // 4608 B
    __shared__ __align__(16) float dt[6][36];               // 864 B

    const int tid = threadIdx.x;
    // XCD swizzle: consecutive resident blocks on one XCD share halo rows.
    const int blk = (blockIdx.x & 7) * 128 + (blockIdx.x >> 3);
    const int b   = blk >> 7;            // 128 blocks per batch
    const int rem = blk & 127;
    const int h0  = (rem >> 2) * 4;
    const int w0  = (rem & 3) * 32;

    // ---- depth loads FIRST (x loads stay in flight behind them) ----
    float dv = 0.f;
    int dr = 0, dcol = 0;
    if (tid < 216) {
        dr = tid / 36; dcol = tid - dr * 36;
        int gh = h0 - 1 + dr, gw = w0 - 1 + dcol;
        bool ok = ((unsigned)gh < (unsigned)H_) && ((unsigned)gw < (unsigned)W_);
        int ghc = gh < 0 ? 0 : (gh > H_ - 1 ? H_ - 1 : gh);
        int gwc = gw < 0 ? 0 : (gw > W_ - 1 ? W_ - 1 : gw);
        float v = depth[(b * H_ + ghc) * W_ + gwc];
        dv = ok ? v : 0.f;
    }

    // ---- issue x loads: paired channels (c = 2*pcr, 2*pcr+1) ----
    const int q   = tid & 7;      // float4 position (w0 + q*4)
    const int pcr = tid >> 3;     // channel pair 0..31
    const int c0p = 2 * pcr;
    float4 xa[6], xb[6];
    bool okh[6];
    #pragma unroll
    for (int r = 0; r < 6; ++r) {
        int gh = h0 - 1 + r;
        okh[r] = (unsigned)gh < (unsigned)H_;
        int ghc = gh < 0 ? 0 : (gh > H_ - 1 ? H_ - 1 : gh);
        const float* base = &x[((b * C_ + c0p) * H_ + ghc) * W_ + w0 + q * 4];
        xa[r] = *(const float4*)base;
        xb[r] = *(const float4*)(base + H_ * W_);
    }
    // halo cols (col 0 and col 33): 2 sides x 6 r x 32 pairs = 384 items
    float hl0[2], hl1[2];
    int hside[2], hcp[2], hr_[2];
    bool hok[2];
    #pragma unroll
    for (int k = 0; k < 2; ++k) {
        int i = tid + 256 * k;
        hok[k] = false;
        if (i < 384) {
            int side = i & 1, rp = i >> 1;
            int cp = rp & 31, r = rp >> 5;
            hside[k] = side; hcp[k] = cp; hr_[k] = r;
            int gh = h0 - 1 + r;
            int gw = side ? (w0 + 32) : (w0 - 1);
            bool ok = ((unsigned)gh < (unsigned)H_) && ((unsigned)gw < (unsigned)W_);
            hok[k] = true;
            int ghc = gh < 0 ? 0 : (gh > H_ - 1 ? H_ - 1 : gh);
            int gwc = gw < 0 ? 0 : (gw > W_ - 1 ? W_ - 1 : gw);
            const float* p = &x[((b * C_ + 2 * cp) * H_ + ghc) * W_ + gwc];
            float v0 = p[0], v1 = p[H_ * W_];
            hl0[k] = ok ? v0 : 0.f;
            hl1[k] = ok ? v1 : 0.f;
        }
    }

    // ---- write depth tile, then sim ----
    if (tid < 216) dt[dr][dcol] = dv;
    __syncthreads();
    for (int i = tid; i < 1152; i += 256) {
        int t  = i >> 7;            // 0..8
        int hr = (i >> 5) & 3;
        int px = i & 31;
        int kh = t / 3, kw = t - kh * 3;
        sim[t][hr][px] = expf(-fabsf(dt[hr + kh][px + kw] - dt[hr + 1][px + 1]));
    }

    // ---- cvt_pk + LDS write x ----
    #pragma unroll
    for (int r = 0; r < 6; ++r) {
        float va[4] = {xa[r].x, xa[r].y, xa[r].z, xa[r].w};
        float vb[4] = {xb[r].x, xb[r].y, xb[r].z, xb[r].w};
        #pragma unroll
        for (int m = 0; m < 4; ++m) {
            int col = 1 + q * 4 + m;
            int rc  = r * 34 + col;
            float2 pr;
            pr.x = okh[r] ? va[m] : 0.f;
            pr.y = okh[r] ? vb[m] : 0.f;
            __hip_bfloat162 bv = __float22bfloat162_rn(pr);
            *(__hip_bfloat162*)(xs + rc * 128 + ((4 * pcr) ^ swz(col))) = bv;
        }
    }
    #pragma unroll
    for (int k = 0; k < 2; ++k) {
        if (hok[k]) {
            int col = hside[k] ? 33 : 0;
            int rc  = hr_[k] * 34 + col;
            float2 pr; pr.x = hl0[k]; pr.y = hl1[k];
            __hip_bfloat162 bv = __float22bfloat162_rn(pr);
            *(__hip_bfloat162*)(xs + rc * 128 + ((4 * hcp[k]) ^ swz(col))) = bv;
        }
    }
    __syncthreads();

    // ---- main loop: barrier-free, wave = output row ----
    const int lane = tid & 63;
    const int hr   = tid >> 6;
    const int g    = lane >> 4;
    const int ln   = lane & 15;

    float acc[2][4][4];
    #pragma unroll
    for (int of = 0; of < 4; ++of) {
        float bv = bias[of * 16 + ln];
        #pragma unroll
        for (int pf = 0; pf < 2; ++pf)
            #pragma unroll
            for (int r = 0; r < 4; ++r)
                acc[pf][of][r] = bv;
    }

    #pragma unroll
    for (int t = 0; t < 9; ++t) {
        const int kh = t / 3, kw = t - (t / 3) * 3;
        bf16x8 bfr[2][4];
        #pragma unroll
        for (int ks = 0; ks < 2; ++ks)
            #pragma unroll
            for (int of = 0; of < 4; ++of)
                bfr[ks][of] = *(const bf16x8*)(
                    wfrag + (((t * 2 + ks) * 4 + of) * 64 + lane) * 8);

        #pragma unroll
        for (int pf = 0; pf < 2; ++pf) {
            int col = pf * 16 + ln + kw;
            int rcb = (hr + kh) * 34 + col;
            const unsigned char* rowp = xs + rcb * 128;
            bf16x8 af0 = *(const bf16x8*)(rowp + ((16 * g) ^ swz(col)));
            bf16x8 af1 = *(const bf16x8*)(rowp + ((64 + 16 * g) ^ swz(col)));

            f32x4 prt[4] = {};
            #pragma unroll
            for (int of = 0; of < 4; ++of)
                prt[of] = __builtin_amdgcn_mfma_f32_16x16x32_bf16(
                    af0, bfr[0][of], prt[of], 0, 0, 0);
            #pragma unroll
            for (int of = 0; of < 4; ++of)
                prt[of] = __builtin_amdgcn_mfma_f32_16x16x32_bf16(
                    af1, bfr[1][of], prt[of], 0, 0, 0);

            f32x4 sv = *(const f32x4*)&sim[t][hr][pf * 16 + g * 4];
            #pragma unroll
            for (int of = 0; of < 4; ++of)
                #pragma unroll
                for (int r = 0; r < 4; ++r)
                    acc[pf][of][r] = fmaf(sv[r], prt[of][r], acc[pf][of][r]);
        }
    }

    // ---- direct stores: 4 g-lanes form 64B chunks ----
    const int h = h0 + hr;
    #pragma unroll
    for (int of = 0; of < 4; ++of) {
        int o = of * 16 + ln;
        float* dst = out + (((size_t)(b * O_ + o) * H_ + h) * W_) + w0;
        #pragma unroll
        for (int pf = 0; pf < 2; ++pf) {
            f32x4 v = { acc[pf][of][0], acc[pf][of][1],
                        acc[pf][of][2], acc[pf][of][3] };
            *(f32x4*)(dst + pf * 16 + g * 4) = v;
        }
    }
}

extern "C" void kernel_launch(void* const* d_in, const int* in_sizes, int n_in,
                              void* d_out, int out_size, void* d_ws, size_t ws_size,
                              hipStream_t stream) {
    const float* x      = (const float*)d_in[0];
    const float* depth  = (const float*)d_in[1];
    const float* weight = (const float*)d_in[2];
    const float* bias   = (const float*)d_in[3];
    float* out          = (float*)d_out;
    unsigned short* wfrag = (unsigned short*)d_ws;   // 73,728 B

    prep_weights<<<dim3(144), dim3(256), 0, stream>>>(weight, wfrag);
    depthconv_mfma5<<<dim3(1024), dim3(256), 0, stream>>>(
        x, depth, wfrag, bias, out);
}

// Round 5
// 36.591 us; speedup vs baseline: 2.4285x; 2.4285x over previous
//
#include <hip/hip_runtime.h>
#include <hip/hip_bf16.h>

#define B_ 8
#define C_ 64
#define O_ 64
#define H_ 128
#define W_ 128

typedef __attribute__((ext_vector_type(8))) short bf16x8;
typedef __attribute__((ext_vector_type(4))) float f32x4;

__device__ __forceinline__ unsigned short f2bf(float v) {
    unsigned u = __float_as_uint(v);
    return (unsigned short)((u + 0x7FFFu + ((u >> 16) & 1u)) >> 16);
}

__device__ __forceinline__ int swz(int col) {   // 16B slot selector
    return ((col ^ (col >> 3)) & 7) << 4;
}

// ---- weight prep: wfrag flat = (((t*2+ks)*4+fi)*64 + lane)*8 + j ----
// o = fi*16 + (lane&15), c = ks*32 + ((lane>>4)&3)*8 + j  (MFMA B-frag order)
__global__ void prep_weights(const float* __restrict__ weight,
                             unsigned short* __restrict__ wfrag) {
    int idx = blockIdx.x * 256 + threadIdx.x;
    if (idx >= 9 * 4096) return;
    int j  = idx & 7;
    int l  = (idx >> 3) & 63;
    int fi = (idx >> 9) & 3;
    int ks = (idx >> 11) & 1;
    int t  = idx >> 12;
    int o  = fi * 16 + (l & 15);
    int c  = ks * 32 + ((l >> 4) & 3) * 8 + j;
    wfrag[idx] = f2bf(weight[(o * C_ + c) * 9 + t]);
}

// Block: (b, 4-row group h0, w-half w0). 4 waves, wave = output row.
// x LDS: bf16 c-innermost: byte(rc = r*66+col, c) = rc*128 + ((2c) ^ swz(col))
// Arena reused by the epilogue: rowid = (o*4+h')  -> 256B row of 64 floats,
// 16B chunk stored at (chunk ^ (rowid>>2 & 15)) for bank spread.
__global__ __launch_bounds__(256, 2)
void depthconv_mfma6(const float* __restrict__ x,
                     const float* __restrict__ depth,
                     const unsigned short* __restrict__ wfrag,
                     const float* __restrict__ bias,
                     float* __restrict__ out) {
    __shared__ __align__(16) unsigned char arena[65536];
    unsigned char* xs   = arena;                                   // [396*128]
    float (*sim)[4][64] = (float (*)[4][64])(arena + 50688);       // [9][4][64]
    float (*dt)[68]     = (float (*)[68])(arena + 59904);          // [6][68]

    const int tid = threadIdx.x;
    const int blk = blockIdx.x;
    const int b   = blk >> 6;            // 64 blocks per batch
    const int rem = blk & 63;
    const int h0  = (rem >> 1) * 4;
    const int w0  = (rem & 1) * 64;

    // ---- stage depth tile (6 x 66) ----
    for (int i = tid; i < 396; i += 256) {
        int r = i / 66, col = i - r * 66;
        int gh = h0 - 1 + r, gw = w0 - 1 + col;
        bool ok = ((unsigned)gh < (unsigned)H_) && ((unsigned)gw < (unsigned)W_);
        int ghc = gh < 0 ? 0 : (gh > H_ - 1 ? H_ - 1 : gh);
        int gwc = gw < 0 ? 0 : (gw > W_ - 1 ? W_ - 1 : gw);
        float v = depth[(b * H_ + ghc) * W_ + gwc];
        dt[r][col] = ok ? v : 0.f;
    }
    __syncthreads();   // dt visible; x loads issued after so barrier drains fast

    // ---- issue x loads: paired channels, 64-col rows ----
    const int q  = tid & 15;      // float4 position: w0 + q*4
    const int pc = tid >> 4;      // 0..15
    float4 xa[12], xb[12];
    #pragma unroll
    for (int k = 0; k < 12; ++k) {
        int r    = k >> 1;
        int pair = pc + 16 * (k & 1);      // 0..31
        int gh   = h0 - 1 + r;
        int ghc  = gh < 0 ? 0 : (gh > H_ - 1 ? H_ - 1 : gh);
        const float* base = &x[((b * C_ + 2 * pair) * H_ + ghc) * W_ + w0 + q * 4];
        xa[k] = *(const float4*)base;
        xb[k] = *(const float4*)(base + H_ * W_);
    }
    // halo cols (col 0 / col 65): 2 sides x 6 r x 32 pairs = 384 items
    float hl0[2], hl1[2];
    int hside[2], hpair[2], hr_[2];
    bool hact[2];
    #pragma unroll
    for (int k = 0; k < 2; ++k) {
        int i = tid + 256 * k;
        hact[k] = false;
        if (i < 384) {
            int side = i & 1, rp = i >> 1;
            int pair = rp & 31, r = rp >> 5;
            hside[k] = side; hpair[k] = pair; hr_[k] = r;
            hact[k] = true;
            int gh = h0 - 1 + r;
            int gw = side ? (w0 + 64) : (w0 - 1);
            bool ok = ((unsigned)gh < (unsigned)H_) && ((unsigned)gw < (unsigned)W_);
            int ghc = gh < 0 ? 0 : (gh > H_ - 1 ? H_ - 1 : gh);
            int gwc = gw < 0 ? 0 : (gw > W_ - 1 ? W_ - 1 : gw);
            const float* p = &x[((b * C_ + 2 * pair) * H_ + ghc) * W_ + gwc];
            float v0 = p[0], v1 = p[H_ * W_];
            hl0[k] = ok ? v0 : 0.f;
            hl1[k] = ok ? v1 : 0.f;
        }
    }

    // ---- sim[t][hr][px] while x loads are in flight ----
    {
        int shr = (tid >> 6) & 3, px = tid & 63;
        float dc = dt[shr + 1][px + 1];
        #pragma unroll
        for (int t = 0; t < 9; ++t) {
            const int kh = t / 3, kw = t % 3;   // compile-time
            sim[t][shr][px] = expf(-fabsf(dt[shr + kh][px + kw] - dc));
        }
    }

    // ---- cvt_pk + LDS write x ----
    #pragma unroll
    for (int k = 0; k < 12; ++k) {
        int r    = k >> 1;
        int pair = pc + 16 * (k & 1);
        int gh   = h0 - 1 + r;
        bool okh = (unsigned)gh < (unsigned)H_;
        float va[4] = {xa[k].x, xa[k].y, xa[k].z, xa[k].w};
        float vb[4] = {xb[k].x, xb[k].y, xb[k].z, xb[k].w};
        #pragma unroll
        for (int m = 0; m < 4; ++m) {
            int col = 1 + q * 4 + m;
            int rc  = r * 66 + col;
            float2 pr;
            pr.x = okh ? va[m] : 0.f;
            pr.y = okh ? vb[m] : 0.f;
            __hip_bfloat162 bv = __float22bfloat162_rn(pr);
            *(__hip_bfloat162*)(xs + rc * 128 + ((4 * pair) ^ swz(col))) = bv;
        }
    }
    #pragma unroll
    for (int k = 0; k < 2; ++k) {
        if (hact[k]) {
            int col = hside[k] ? 65 : 0;
            int rc  = hr_[k] * 66 + col;
            float2 pr; pr.x = hl0[k]; pr.y = hl1[k];
            __hip_bfloat162 bv = __float22bfloat162_rn(pr);
            *(__hip_bfloat162*)(xs + rc * 128 + ((4 * hpair[k]) ^ swz(col))) = bv;
        }
    }
    __syncthreads();

    // ---- main loop: barrier-free, wave = output row ----
    const int lane = tid & 63;
    const int hr   = tid >> 6;
    const int g    = lane >> 4;
    const int ln   = lane & 15;

    float acc[4][4][4];
    #pragma unroll
    for (int of = 0; of < 4; ++of) {
        float bv = bias[of * 16 + ln];
        #pragma unroll
        for (int pf = 0; pf < 4; ++pf)
            #pragma unroll
            for (int r = 0; r < 4; ++r)
                acc[pf][of][r] = bv;
    }

    #pragma unroll 1
    for (int kh = 0; kh < 3; ++kh) {
        #pragma unroll
        for (int kw = 0; kw < 3; ++kw) {
            const int t = kh * 3 + kw;
            bf16x8 bfr[2][4];
            #pragma unroll
            for (int ks = 0; ks < 2; ++ks)
                #pragma unroll
                for (int of = 0; of < 4; ++of)
                    bfr[ks][of] = *(const bf16x8*)(
                        wfrag + (((t * 2 + ks) * 4 + of) * 64 + lane) * 8);

            #pragma unroll
            for (int pf = 0; pf < 4; ++pf) {
                int col = pf * 16 + ln + kw;
                int rcb = (hr + kh) * 66 + col;
                const unsigned char* rowp = xs + rcb * 128;
                bf16x8 af0 = *(const bf16x8*)(rowp + ((16 * g) ^ swz(col)));
                bf16x8 af1 = *(const bf16x8*)(rowp + ((64 + 16 * g) ^ swz(col)));

                f32x4 prt[4] = {};
                #pragma unroll
                for (int of = 0; of < 4; ++of)
                    prt[of] = __builtin_amdgcn_mfma_f32_16x16x32_bf16(
                        af0, bfr[0][of], prt[of], 0, 0, 0);
                #pragma unroll
                for (int of = 0; of < 4; ++of)
                    prt[of] = __builtin_amdgcn_mfma_f32_16x16x32_bf16(
                        af1, bfr[1][of], prt[of], 0, 0, 0);

                f32x4 sv = *(const f32x4*)&sim[t][hr][pf * 16 + g * 4];
                #pragma unroll
                for (int of = 0; of < 4; ++of)
                    #pragma unroll
                    for (int r = 0; r < 4; ++r)
                        acc[pf][of][r] = fmaf(sv[r], prt[of][r], acc[pf][of][r]);
            }
        }
    }

    // ---- epilogue: LDS transpose -> fully-coalesced 256B-span stores ----
    __syncthreads();   // done reading xs/sim; arena is reused below
    #pragma unroll
    for (int pf = 0; pf < 4; ++pf)
        #pragma unroll
        for (int of = 0; of < 4; ++of) {
            int rowid = ((of * 16 + ln) << 2) + hr;   // (o*4 + h')
            int chunk = (pf << 2) + g;                // 16B chunk in row
            f32x4 v = { acc[pf][of][0], acc[pf][of][1],
                        acc[pf][of][2], acc[pf][of][3] };
            *(f32x4*)(arena + rowid * 256 + ((chunk ^ ln) << 4)) = v;
        }
    __syncthreads();
    #pragma unroll
    for (int m = 0; m < 16; ++m) {
        int idx   = m * 256 + tid;
        int rowid = idx >> 4;
        int cc    = idx & 15;
        int key   = (rowid >> 2) & 15;
        f32x4 v = *(const f32x4*)(arena + rowid * 256 + ((cc ^ key) << 4));
        int o  = rowid >> 2;
        int hh = rowid & 3;
        *(f32x4*)(out + (((size_t)(b * O_ + o) * H_ + h0 + hh) * W_) + w0 + cc * 4) = v;
    }
}

extern "C" void kernel_launch(void* const* d_in, const int* in_sizes, int n_in,
                              void* d_out, int out_size, void* d_ws, size_t ws_size,
                              hipStream_t stream) {
    const float* x      = (const float*)d_in[0];
    const float* depth  = (const float*)d_in[1];
    const float* weight = (const float*)d_in[2];
    const float* bias   = (const float*)d_in[3];
    float* out          = (float*)d_out;
    unsigned short* wfrag = (unsigned short*)d_ws;   // 73,728 B

    prep_weights<<<dim3(144), dim3(256), 0, stream>>>(weight, wfrag);
    depthconv_mfma6<<<dim3(512), dim3(256), 0, stream>>>(
        x, depth, wfrag, bias, out);
}